// Round 14
// baseline (60.808 us; speedup 1.0000x reference)
//
#include <hip/hip_runtime.h>
#include <hip/hip_bf16.h>
#include <math.h>

// Problem constants (B=4, T=2048, D=1024, H=64), fp32 in/out.
#define Bb   4
#define Tlen 2048
#define Dd   1024
#define Hh   64
#define NROWS 8192      // B*T
#define NQ   32         // q-tiles of 64 rows per batch
#define NC   4          // flash-decoding split

typedef short bf16x8 __attribute__((ext_vector_type(8)));
typedef float f32x4  __attribute__((ext_vector_type(4)));

__device__ __forceinline__ unsigned short f2b(float f) {
    unsigned u = __float_as_uint(f);
    unsigned r = u + 0x7FFFu + ((u >> 16) & 1u);   // RNE
    return (unsigned short)(r >> 16);
}
__device__ __forceinline__ unsigned pk2(float a, float b) {   // 2xf32 -> packed bf16x2 (RNE)
    __hip_bfloat162 h = __float22bfloat162_rn(make_float2(a, b));
    return *reinterpret_cast<unsigned*>(&h);
}

// ---------------- Kernel 0: W -> MFMA B-fragment layout ----------------
__global__ __launch_bounds__(256) void wtrans_kernel(
    const float* __restrict__ Wq, const float* __restrict__ Wk,
    const float* __restrict__ Wv, unsigned short* __restrict__ wfrag)
{
    const int s = blockIdx.x * 256 + threadIdx.x;    // 0..24575
    const int f   = s / 768;
    const int rem = s % 768;
    const int nb  = rem >> 6;
    const int lane = rem & 63;
    const int g = lane >> 4, qr = lane & 15;
    const int n = nb * 16 + qr;
    const int wsel = n >> 6, h = n & 63;
    const float* W = (wsel == 0) ? Wq : (wsel == 1) ? Wk : Wv;
    const int k0 = (f >> 1) * 64 + (f & 1) * 32 + g * 8;
    unsigned short tmp[8];
    #pragma unroll
    for (int j = 0; j < 8; ++j) tmp[j] = f2b(W[(size_t)(k0 + j) * Hh + h]);
    *(bf16x8*)(wfrag + (size_t)s * 8) = *(const bf16x8*)tmp;
}

// ---------------- Kernel 1: QKV projection (round-13: x + W reg-prefetch) ----------------
// q,k written row-major [row][h]; V written TRANSPOSED: vwT[b][h][t] so attn
// can load PV B-fragments directly from global (no LDS V transpose).
__global__ __launch_bounds__(256) void proj_kernel(
    const float* __restrict__ x, const unsigned short* __restrict__ wfrag,
    unsigned short* __restrict__ qw, unsigned short* __restrict__ kw,
    unsigned short* __restrict__ vwT)
{
    __shared__ unsigned short xs[2][32 * 64];

    const int rb   = blockIdx.x * 32;
    const int tid  = threadIdx.x;
    const int wv   = tid >> 6;
    const int lane = tid & 63;
    const int qr   = lane & 15;
    const int g    = lane >> 4;

    const int xr = tid >> 3, xc8 = tid & 7;
    const float* xg0 = x + (size_t)(rb + xr) * Dd + xc8 * 8;

    const unsigned short* wp = wfrag + ((size_t)(wv * 3) * 64 + lane) * 8;

    f32x4 acc[6] = {};   // [mf][nf]

    float4 px0 = *(const float4*)(xg0 + 0);
    float4 px1 = *(const float4*)(xg0 + 4);

    bf16x8 wr[6];
    #pragma unroll
    for (int ks = 0; ks < 2; ++ks)
        #pragma unroll
        for (int nf = 0; nf < 3; ++nf)
            wr[ks * 3 + nf] = *(const bf16x8*)(wp + (size_t)(ks * 12 + nf) * 512);

    #pragma unroll
    for (int t = 0; t < 16; ++t) {
        const int cur = t & 1;
        {   // stage x(t) from regs
            union { unsigned u[4]; bf16x8 v; } p8;
            p8.u[0] = pk2(px0.x, px0.y);
            p8.u[1] = pk2(px0.z, px0.w);
            p8.u[2] = pk2(px1.x, px1.y);
            p8.u[3] = pk2(px1.z, px1.w);
            *(bf16x8*)(&xs[cur][xr * 64 + ((xc8 ^ (xr & 7)) << 3)]) = p8.v;
        }
        __syncthreads();

        bf16x8 wn[6];
        if (t < 15) {
            px0 = *(const float4*)(xg0 + (t + 1) * 64 + 0);
            px1 = *(const float4*)(xg0 + (t + 1) * 64 + 4);
            const int fb = (t + 1) * 2;
            #pragma unroll
            for (int ks = 0; ks < 2; ++ks)
                #pragma unroll
                for (int nf = 0; nf < 3; ++nf)
                    wn[ks * 3 + nf] = *(const bf16x8*)(wp + (size_t)((fb + ks) * 12 + nf) * 512);
        }

        #pragma unroll
        for (int ks = 0; ks < 2; ++ks) {
            #pragma unroll
            for (int mf = 0; mf < 2; ++mf) {
                const int arow = mf * 16 + qr;
                const bf16x8 a = *(const bf16x8*)(
                    &xs[cur][arow * 64 + (((ks * 4 + g) ^ (arow & 7)) << 3)]);
                acc[mf * 3 + 0] = __builtin_amdgcn_mfma_f32_16x16x32_bf16(a, wr[ks * 3 + 0], acc[mf * 3 + 0], 0, 0, 0);
                acc[mf * 3 + 1] = __builtin_amdgcn_mfma_f32_16x16x32_bf16(a, wr[ks * 3 + 1], acc[mf * 3 + 1], 0, 0, 0);
                acc[mf * 3 + 2] = __builtin_amdgcn_mfma_f32_16x16x32_bf16(a, wr[ks * 3 + 2], acc[mf * 3 + 2], 0, 0, 0);
            }
        }
        __syncthreads();

        if (t < 15) {
            #pragma unroll
            for (int i = 0; i < 6; ++i) wr[i] = wn[i];
        }
    }

    #pragma unroll
    for (int mf = 0; mf < 2; ++mf) {
        #pragma unroll
        for (int nf = 0; nf < 3; ++nf) {
            const int n = wv * 48 + nf * 16 + qr;
            const int wsel = n >> 6, h = n & 63;
            const f32x4 ov = acc[mf * 3 + nf];
            #pragma unroll
            for (int r = 0; r < 4; ++r) {
                const int row = rb + mf * 16 + 4 * g + r;
                if (wsel == 2) {
                    // vwT[b][h][t]: b = row>>11, t = row&2047
                    vwT[((size_t)(row >> 11) * Hh + h) * Tlen + (row & 2047)] = f2b(ov[r]);
                } else {
                    unsigned short* out = (wsel == 0) ? qw : kw;
                    out[(size_t)row * Hh + h] = f2b(ov[r]);
                }
            }
        }
    }
}

// ---------------- Kernel 2: flash attention partials — NO LDS, NO BARRIERS ----------------
// grid (NQ, NC, B), 4 independent waves per block. K A-frags and V^T B-frags
// loaded straight from global (L2-resident), register-prefetched one tile ahead.
__global__ __launch_bounds__(256) void attn_kernel(
    const unsigned short* __restrict__ qw, const unsigned short* __restrict__ kw,
    const unsigned short* __restrict__ vwT,
    float* __restrict__ part_O, float* __restrict__ part_ml)
{
    const int qt = (NQ - 1) - blockIdx.x;   // big q-tiles dispatched first
    const int ci = blockIdx.y;
    const int b  = blockIdx.z;
    const int tid = threadIdx.x;
    const int wv = tid >> 6, lane = tid & 63;
    const int qr = lane & 15, g = lane >> 4;

    const int ntk = 2 * qt + 2;                    // causal key tiles of 32
    const int tpc = (ntk + NC - 1) / NC;
    const int t0  = ci * tpc;
    const int t1  = (ntk < t0 + tpc) ? ntk : (t0 + tpc);

    const size_t base = (size_t)b * Tlen * Hh;
    const unsigned short* kwb = kw + base;
    const unsigned short* vtb = vwT + (size_t)b * Hh * Tlen;   // [h][t]
    const int qrow = qt * 64 + wv * 16 + qr;

    const bf16x8 qf0 = *(const bf16x8*)(qw + base + (size_t)qrow * Hh + 8 * g);
    const bf16x8 qf1 = *(const bf16x8*)(qw + base + (size_t)qrow * Hh + 32 + 8 * g);

    f32x4 o0 = {}, o1 = {}, o2 = {}, o3 = {};
    float m = -INFINITY, l = 0.f;

    // per-lane fragment sources (element offsets into kwb / vtb)
    // K A-frag (jf,ks): (j0 + jf*16 + qr)*64 + ks*32 + g*8
    // V B-frag (nf):    (nf*16 + qr)*2048 + j0 + g*8
    const size_t kO = (size_t)qr * 64 + g * 8;
    const size_t vO = (size_t)qr * 2048 + g * 8;

    bf16x8 kf[4], vf[4];
    if (t0 < t1) {
        const size_t j64 = (size_t)t0 * 32 * 64;
        kf[0] = *(const bf16x8*)(kwb + j64 + kO);
        kf[1] = *(const bf16x8*)(kwb + j64 + kO + 32);
        kf[2] = *(const bf16x8*)(kwb + j64 + kO + 16 * 64);
        kf[3] = *(const bf16x8*)(kwb + j64 + kO + 16 * 64 + 32);
        vf[0] = *(const bf16x8*)(vtb + vO + t0 * 32);
        vf[1] = *(const bf16x8*)(vtb + vO + 16 * 2048 + t0 * 32);
        vf[2] = *(const bf16x8*)(vtb + vO + 32 * 2048 + t0 * 32);
        vf[3] = *(const bf16x8*)(vtb + vO + 48 * 2048 + t0 * 32);
    }

    for (int kt = t0; kt < t1; ++kt) {
        const int j0 = kt * 32;

        // prefetch next tile's 8 fragments (full tile of compute to hide under)
        bf16x8 kn[4], vn[4];
        if (kt + 1 < t1) {
            const size_t j64 = (size_t)(kt + 1) * 32 * 64;
            kn[0] = *(const bf16x8*)(kwb + j64 + kO);
            kn[1] = *(const bf16x8*)(kwb + j64 + kO + 32);
            kn[2] = *(const bf16x8*)(kwb + j64 + kO + 16 * 64);
            kn[3] = *(const bf16x8*)(kwb + j64 + kO + 16 * 64 + 32);
            vn[0] = *(const bf16x8*)(vtb + vO + (kt + 1) * 32);
            vn[1] = *(const bf16x8*)(vtb + vO + 16 * 2048 + (kt + 1) * 32);
            vn[2] = *(const bf16x8*)(vtb + vO + 32 * 2048 + (kt + 1) * 32);
            vn[3] = *(const bf16x8*)(vtb + vO + 48 * 2048 + (kt + 1) * 32);
        }

        // S^T = K . Q^T
        f32x4 a0 = {}, a1 = {};
        a0 = __builtin_amdgcn_mfma_f32_16x16x32_bf16(kf[0], qf0, a0, 0, 0, 0);
        a0 = __builtin_amdgcn_mfma_f32_16x16x32_bf16(kf[1], qf1, a0, 0, 0, 0);
        a1 = __builtin_amdgcn_mfma_f32_16x16x32_bf16(kf[2], qf0, a1, 0, 0, 0);
        a1 = __builtin_amdgcn_mfma_f32_16x16x32_bf16(kf[3], qf1, a1, 0, 0, 0);

        // masked scores + online softmax (round-13 trims)
        float p[8];
        float tm = -INFINITY;
        #pragma unroll
        for (int jf = 0; jf < 2; ++jf) {
            #pragma unroll
            for (int r = 0; r < 4; ++r) {
                const int jg = j0 + jf * 16 + 4 * g + r;
                float s = ((jf == 0) ? a0[r] : a1[r]) * 0.125f;
                s = (jg > qrow) ? -INFINITY : s;
                p[jf * 4 + r] = s;
                tm = fmaxf(tm, s);
            }
        }
        tm = fmaxf(tm, __shfl_xor(tm, 16));
        tm = fmaxf(tm, __shfl_xor(tm, 32));
        const float mnew = fmaxf(m, tm);
        const float mc   = fmaxf(mnew, -1e30f);
        float psum = 0.f;
        #pragma unroll
        for (int i = 0; i < 8; ++i) {
            const float pv = __expf(p[i] - mc);
            p[i] = pv; psum += pv;
        }
        psum += __shfl_xor(psum, 16);
        psum += __shfl_xor(psum, 32);

        if (!__all(tm <= m)) {
            const float alpha = (m == -INFINITY) ? 0.f : __expf(m - mc);
            const float ar0 = __shfl(alpha, 4 * g + 0);
            const float ar1 = __shfl(alpha, 4 * g + 1);
            const float ar2 = __shfl(alpha, 4 * g + 2);
            const float ar3 = __shfl(alpha, 4 * g + 3);
            o0[0] *= ar0; o0[1] *= ar1; o0[2] *= ar2; o0[3] *= ar3;
            o1[0] *= ar0; o1[1] *= ar1; o1[2] *= ar2; o1[3] *= ar3;
            o2[0] *= ar0; o2[1] *= ar1; o2[2] *= ar2; o2[3] *= ar3;
            o3[0] *= ar0; o3[1] *= ar1; o3[2] *= ar2; o3[3] *= ar3;
            l = l * alpha + psum;
        } else {
            l += psum;
        }
        m = mnew;

        // repack P (S^T layout) -> PV A-fragment
        unsigned pw[4];
        pw[0] = f2b(p[0]) | ((unsigned)f2b(p[1]) << 16);
        pw[1] = f2b(p[2]) | ((unsigned)f2b(p[3]) << 16);
        pw[2] = f2b(p[4]) | ((unsigned)f2b(p[5]) << 16);
        pw[3] = f2b(p[6]) | ((unsigned)f2b(p[7]) << 16);
        union PU { unsigned u[4]; bf16x8 v; } pu;
        #pragma unroll
        for (int w = 0; w < 4; ++w) {
            const int gp  = 2 * g + (w >> 1);
            const int src = 16 * (gp & 3) + qr;
            const unsigned t0s = __shfl(pw[0 + (w & 1)], src);
            const unsigned t1s = __shfl(pw[2 + (w & 1)], src);
            pu.u[w] = (gp & 4) ? t1s : t0s;
        }
        const bf16x8 pa = pu.v;

        // O += P . V  (B-frags direct from vwT)
        o0 = __builtin_amdgcn_mfma_f32_16x16x32_bf16(pa, vf[0], o0, 0, 0, 0);
        o1 = __builtin_amdgcn_mfma_f32_16x16x32_bf16(pa, vf[1], o1, 0, 0, 0);
        o2 = __builtin_amdgcn_mfma_f32_16x16x32_bf16(pa, vf[2], o2, 0, 0, 0);
        o3 = __builtin_amdgcn_mfma_f32_16x16x32_bf16(pa, vf[3], o3, 0, 0, 0);

        if (kt + 1 < t1) {
            #pragma unroll
            for (int i = 0; i < 4; ++i) { kf[i] = kn[i]; vf[i] = vn[i]; }
        }
    }

    // write partials (unnormalized O', m, l)
    const int blin = (b * NQ + qt) * NC + ci;
    float* po = part_O + (size_t)blin * 4096;
    #pragma unroll
    for (int nf = 0; nf < 4; ++nf) {
        const f32x4 ov = (nf == 0) ? o0 : (nf == 1) ? o1 : (nf == 2) ? o2 : o3;
        #pragma unroll
        for (int r = 0; r < 4; ++r)
            po[(size_t)(wv * 16 + 4 * g + r) * 64 + nf * 16 + qr] = ov[r];
    }
    if (g == 0) {
        part_ml[(size_t)blin * 128 + wv * 16 + qr]      = m;
        part_ml[(size_t)blin * 128 + 64 + wv * 16 + qr] = l;
    }
}

// ---------------- Kernel 3: merge partials ----------------
__global__ __launch_bounds__(256) void merge_kernel(
    const float* __restrict__ part_O, const float* __restrict__ part_ml,
    float* __restrict__ out)
{
    const int idx = blockIdx.x * 256 + threadIdx.x;   // 0 .. 524287
    const int row = idx >> 6;
    const int c   = idx & 63;
    const int b   = row >> 11;
    const int t   = row & 2047;
    const int qt  = t >> 6;
    const int qq  = t & 63;
    const int bl0 = (b * NQ + qt) * NC;

    float M = -INFINITY;
    #pragma unroll
    for (int i = 0; i < NC; ++i) {
        const float lvi = part_ml[(size_t)(bl0 + i) * 128 + 64 + qq];
        if (lvi > 0.f) M = fmaxf(M, part_ml[(size_t)(bl0 + i) * 128 + qq]);
    }
    float num = 0.f, den = 0.f;
    #pragma unroll
    for (int i = 0; i < NC; ++i) {
        const float lvi = part_ml[(size_t)(bl0 + i) * 128 + 64 + qq];
        if (lvi > 0.f) {
            const float wgt = __expf(part_ml[(size_t)(bl0 + i) * 128 + qq] - M);
            num += wgt * part_O[(size_t)(bl0 + i) * 4096 + (size_t)qq * 64 + c];
            den += wgt * lvi;
        }
    }
    out[(size_t)row * 64 + c] = num / den;
}

extern "C" void kernel_launch(void* const* d_in, const int* in_sizes, int n_in,
                              void* d_out, int out_size, void* d_ws, size_t ws_size,
                              hipStream_t stream) {
    const float* x  = (const float*)d_in[0];
    const float* Wq = (const float*)d_in[1];
    const float* Wk = (const float*)d_in[2];
    const float* Wv = (const float*)d_in[3];
    float* outp = (float*)d_out;

    unsigned short* wfrag = (unsigned short*)d_ws;      // 192*1024 bf16
    unsigned short* qw  = wfrag + 192 * 1024;           // 8192*64 each
    unsigned short* kw  = qw + NROWS * Hh;
    unsigned short* vwT = kw + NROWS * Hh;              // [b][h][t]
    float* part_O  = (float*)(vwT + NROWS * Hh);        // (Bb*NQ*NC) * 4096
    float* part_ml = part_O + (size_t)(Bb * NQ * NC) * 4096;

    wtrans_kernel<<<dim3(96), 256, 0, stream>>>(Wq, Wk, Wv, wfrag);
    proj_kernel<<<dim3(NROWS / 32), 256, 0, stream>>>(x, wfrag, qw, kw, vwT);
    attn_kernel<<<dim3(NQ, NC, Bb), 256, 0, stream>>>(qw, kw, vwT, part_O, part_ml);
    merge_kernel<<<dim3((NROWS * Hh) / 256), 256, 0, stream>>>(part_O, part_ml, outp);
}

// Round 15
// 46.673 us; speedup vs baseline: 1.3028x; 1.3028x over previous
//
#include <hip/hip_runtime.h>
#include <hip/hip_bf16.h>
#include <math.h>

// Problem constants (B=4, T=2048, D=1024, H=64), fp32 in/out.
#define Bb   4
#define Tlen 2048
#define Dd   1024
#define Hh   64
#define NROWS 8192      // B*T
#define NQ   32         // q-tiles of 64 rows per batch
#define NC   4          // flash-decoding split

typedef short bf16x8 __attribute__((ext_vector_type(8)));
typedef float f32x4  __attribute__((ext_vector_type(4)));

__device__ __forceinline__ unsigned short f2b(float f) {
    unsigned u = __float_as_uint(f);
    unsigned r = u + 0x7FFFu + ((u >> 16) & 1u);   // RNE
    return (unsigned short)(r >> 16);
}
__device__ __forceinline__ unsigned pk2(float a, float b) {   // 2xf32 -> packed bf16x2 (RNE)
    __hip_bfloat162 h = __float22bfloat162_rn(make_float2(a, b));
    return *reinterpret_cast<unsigned*>(&h);
}

// ---------------- Kernel 0: W -> MFMA B-fragment layout ----------------
__global__ __launch_bounds__(256) void wtrans_kernel(
    const float* __restrict__ Wq, const float* __restrict__ Wk,
    const float* __restrict__ Wv, unsigned short* __restrict__ wfrag)
{
    const int s = blockIdx.x * 256 + threadIdx.x;    // 0..24575
    const int f   = s / 768;
    const int rem = s % 768;
    const int nb  = rem >> 6;
    const int lane = rem & 63;
    const int g = lane >> 4, qr = lane & 15;
    const int n = nb * 16 + qr;
    const int wsel = n >> 6, h = n & 63;
    const float* W = (wsel == 0) ? Wq : (wsel == 1) ? Wk : Wv;
    const int k0 = (f >> 1) * 64 + (f & 1) * 32 + g * 8;
    unsigned short tmp[8];
    #pragma unroll
    for (int j = 0; j < 8; ++j) tmp[j] = f2b(W[(size_t)(k0 + j) * Hh + h]);
    *(bf16x8*)(wfrag + (size_t)s * 8) = *(const bf16x8*)tmp;
}

// ---------------- Kernel 1: QKV projection (round-13 body; K,V written in frag layout) ----------------
// Q row-major [row][h]. K -> kfrag[((b*128+t16)*2+ks)*64+lane]*8+e  (A-frag for
// swapped QK^T). V -> vfrag[((b*64+kt)*4+nf)*64+lane]*8+e (V^T B-frag for PV).
// Attn then loads every fragment as a contiguous, coalesced 1KB wave load.
__global__ __launch_bounds__(256) void proj_kernel(
    const float* __restrict__ x, const unsigned short* __restrict__ wfrag,
    unsigned short* __restrict__ qw, unsigned short* __restrict__ kfr,
    unsigned short* __restrict__ vfr)
{
    __shared__ unsigned short xs[2][32 * 64];

    const int rb   = blockIdx.x * 32;
    const int tid  = threadIdx.x;
    const int wv   = tid >> 6;
    const int lane = tid & 63;
    const int qr   = lane & 15;
    const int g    = lane >> 4;

    const int xr = tid >> 3, xc8 = tid & 7;
    const float* xg0 = x + (size_t)(rb + xr) * Dd + xc8 * 8;

    const unsigned short* wp = wfrag + ((size_t)(wv * 3) * 64 + lane) * 8;

    f32x4 acc[6] = {};   // [mf][nf]

    float4 px0 = *(const float4*)(xg0 + 0);
    float4 px1 = *(const float4*)(xg0 + 4);

    bf16x8 wr[6];
    #pragma unroll
    for (int ks = 0; ks < 2; ++ks)
        #pragma unroll
        for (int nf = 0; nf < 3; ++nf)
            wr[ks * 3 + nf] = *(const bf16x8*)(wp + (size_t)(ks * 12 + nf) * 512);

    #pragma unroll
    for (int t = 0; t < 16; ++t) {
        const int cur = t & 1;
        {   // stage x(t) from regs
            union { unsigned u[4]; bf16x8 v; } p8;
            p8.u[0] = pk2(px0.x, px0.y);
            p8.u[1] = pk2(px0.z, px0.w);
            p8.u[2] = pk2(px1.x, px1.y);
            p8.u[3] = pk2(px1.z, px1.w);
            *(bf16x8*)(&xs[cur][xr * 64 + ((xc8 ^ (xr & 7)) << 3)]) = p8.v;
        }
        __syncthreads();

        bf16x8 wn[6];
        if (t < 15) {
            px0 = *(const float4*)(xg0 + (t + 1) * 64 + 0);
            px1 = *(const float4*)(xg0 + (t + 1) * 64 + 4);
            const int fb = (t + 1) * 2;
            #pragma unroll
            for (int ks = 0; ks < 2; ++ks)
                #pragma unroll
                for (int nf = 0; nf < 3; ++nf)
                    wn[ks * 3 + nf] = *(const bf16x8*)(wp + (size_t)((fb + ks) * 12 + nf) * 512);
        }

        #pragma unroll
        for (int ks = 0; ks < 2; ++ks) {
            #pragma unroll
            for (int mf = 0; mf < 2; ++mf) {
                const int arow = mf * 16 + qr;
                const bf16x8 a = *(const bf16x8*)(
                    &xs[cur][arow * 64 + (((ks * 4 + g) ^ (arow & 7)) << 3)]);
                acc[mf * 3 + 0] = __builtin_amdgcn_mfma_f32_16x16x32_bf16(a, wr[ks * 3 + 0], acc[mf * 3 + 0], 0, 0, 0);
                acc[mf * 3 + 1] = __builtin_amdgcn_mfma_f32_16x16x32_bf16(a, wr[ks * 3 + 1], acc[mf * 3 + 1], 0, 0, 0);
                acc[mf * 3 + 2] = __builtin_amdgcn_mfma_f32_16x16x32_bf16(a, wr[ks * 3 + 2], acc[mf * 3 + 2], 0, 0, 0);
            }
        }
        __syncthreads();

        if (t < 15) {
            #pragma unroll
            for (int i = 0; i < 6; ++i) wr[i] = wn[i];
        }
    }

    // epilogue: scalar stores; K and V go to fragment-major layouts
    #pragma unroll
    for (int mf = 0; mf < 2; ++mf) {
        #pragma unroll
        for (int nf0 = 0; nf0 < 3; ++nf0) {
            const int n = wv * 48 + nf0 * 16 + qr;
            const int wsel = n >> 6, h = n & 63;
            const f32x4 ov = acc[mf * 3 + nf0];
            #pragma unroll
            for (int r = 0; r < 4; ++r) {
                const int row = rb + mf * 16 + 4 * g + r;
                const unsigned short val = f2b(ov[r]);
                if (wsel == 0) {
                    qw[(size_t)row * Hh + h] = val;
                } else if (wsel == 1) {
                    const int bq = row >> 11, t = row & 2047;
                    const int t16 = t >> 4, qrk = t & 15;
                    const int ks = h >> 5, gk = (h >> 3) & 3, e = h & 7;
                    kfr[((((size_t)bq * 128 + t16) * 2 + ks) * 64 + gk * 16 + qrk) * 8 + e] = val;
                } else {
                    const int bq = row >> 11, t = row & 2047;
                    const int kt = t >> 5, jj = t & 31;
                    const int gv = jj >> 3, e = jj & 7;
                    const int nfv = h >> 4, qrv = h & 15;
                    vfr[((((size_t)bq * 64 + kt) * 4 + nfv) * 64 + gv * 16 + qrv) * 8 + e] = val;
                }
            }
        }
    }
}

// ---------------- Kernel 2: flash attention — NO LDS, NO BARRIERS, coalesced frags ----------------
// grid (NQ, NC, B), 4 independent waves/block. Every K/V fragment is a
// contiguous 1KB wave load from the frag-major buffers (L1-broadcast across
// the 4 waves), register-prefetched one tile ahead.
__global__ __launch_bounds__(256) void attn_kernel(
    const unsigned short* __restrict__ qw, const unsigned short* __restrict__ kfr,
    const unsigned short* __restrict__ vfr,
    float* __restrict__ part_O, float* __restrict__ part_ml)
{
    const int qt = (NQ - 1) - blockIdx.x;   // big q-tiles dispatched first
    const int ci = blockIdx.y;
    const int b  = blockIdx.z;
    const int tid = threadIdx.x;
    const int wv = tid >> 6, lane = tid & 63;
    const int qr = lane & 15, g = lane >> 4;

    const int ntk = 2 * qt + 2;                    // causal key tiles of 32
    const int tpc = (ntk + NC - 1) / NC;
    const int t0  = ci * tpc;
    const int t1  = (ntk < t0 + tpc) ? ntk : (t0 + tpc);

    const size_t base = (size_t)b * Tlen * Hh;
    const unsigned short* kfb = kfr + (size_t)b * 131072 + lane * 8;  // 128*2*64*8
    const unsigned short* vfb = vfr + (size_t)b * 131072 + lane * 8;  // 64*4*64*8
    const int qrow = qt * 64 + wv * 16 + qr;

    const bf16x8 qf0 = *(const bf16x8*)(qw + base + (size_t)qrow * Hh + 8 * g);
    const bf16x8 qf1 = *(const bf16x8*)(qw + base + (size_t)qrow * Hh + 32 + 8 * g);

    f32x4 o0 = {}, o1 = {}, o2 = {}, o3 = {};
    float m = -INFINITY, l = 0.f;

    bf16x8 kf[4], vf[4];
    if (t0 < t1) {
        #pragma unroll
        for (int i = 0; i < 4; ++i) {
            kf[i] = *(const bf16x8*)(kfb + (size_t)(t0 * 4 + i) * 512);
            vf[i] = *(const bf16x8*)(vfb + (size_t)(t0 * 4 + i) * 512);
        }
    }

    for (int kt = t0; kt < t1; ++kt) {
        const int j0 = kt * 32;

        // prefetch next tile's 8 fragments (full tile of compute to hide under)
        bf16x8 kn[4], vn[4];
        if (kt + 1 < t1) {
            #pragma unroll
            for (int i = 0; i < 4; ++i) {
                kn[i] = *(const bf16x8*)(kfb + (size_t)((kt + 1) * 4 + i) * 512);
                vn[i] = *(const bf16x8*)(vfb + (size_t)((kt + 1) * 4 + i) * 512);
            }
        }

        // S^T = K . Q^T   (kf idx = jf*2 + ks)
        f32x4 a0 = {}, a1 = {};
        a0 = __builtin_amdgcn_mfma_f32_16x16x32_bf16(kf[0], qf0, a0, 0, 0, 0);
        a0 = __builtin_amdgcn_mfma_f32_16x16x32_bf16(kf[1], qf1, a0, 0, 0, 0);
        a1 = __builtin_amdgcn_mfma_f32_16x16x32_bf16(kf[2], qf0, a1, 0, 0, 0);
        a1 = __builtin_amdgcn_mfma_f32_16x16x32_bf16(kf[3], qf1, a1, 0, 0, 0);

        // masked scores + online softmax (trimmed)
        float p[8];
        float tm = -INFINITY;
        #pragma unroll
        for (int jf = 0; jf < 2; ++jf) {
            #pragma unroll
            for (int r = 0; r < 4; ++r) {
                const int jg = j0 + jf * 16 + 4 * g + r;
                float s = ((jf == 0) ? a0[r] : a1[r]) * 0.125f;
                s = (jg > qrow) ? -INFINITY : s;
                p[jf * 4 + r] = s;
                tm = fmaxf(tm, s);
            }
        }
        tm = fmaxf(tm, __shfl_xor(tm, 16));
        tm = fmaxf(tm, __shfl_xor(tm, 32));
        const float mnew = fmaxf(m, tm);
        const float mc   = fmaxf(mnew, -1e30f);
        float psum = 0.f;
        #pragma unroll
        for (int i = 0; i < 8; ++i) {
            const float pv = __expf(p[i] - mc);
            p[i] = pv; psum += pv;
        }
        psum += __shfl_xor(psum, 16);
        psum += __shfl_xor(psum, 32);

        if (!__all(tm <= m)) {
            const float alpha = (m == -INFINITY) ? 0.f : __expf(m - mc);
            const float ar0 = __shfl(alpha, 4 * g + 0);
            const float ar1 = __shfl(alpha, 4 * g + 1);
            const float ar2 = __shfl(alpha, 4 * g + 2);
            const float ar3 = __shfl(alpha, 4 * g + 3);
            o0[0] *= ar0; o0[1] *= ar1; o0[2] *= ar2; o0[3] *= ar3;
            o1[0] *= ar0; o1[1] *= ar1; o1[2] *= ar2; o1[3] *= ar3;
            o2[0] *= ar0; o2[1] *= ar1; o2[2] *= ar2; o2[3] *= ar3;
            o3[0] *= ar0; o3[1] *= ar1; o3[2] *= ar2; o3[3] *= ar3;
            l = l * alpha + psum;
        } else {
            l += psum;
        }
        m = mnew;

        // repack P (S^T layout) -> PV A-fragment
        unsigned pw[4];
        pw[0] = f2b(p[0]) | ((unsigned)f2b(p[1]) << 16);
        pw[1] = f2b(p[2]) | ((unsigned)f2b(p[3]) << 16);
        pw[2] = f2b(p[4]) | ((unsigned)f2b(p[5]) << 16);
        pw[3] = f2b(p[6]) | ((unsigned)f2b(p[7]) << 16);
        union PU { unsigned u[4]; bf16x8 v; } pu;
        #pragma unroll
        for (int w = 0; w < 4; ++w) {
            const int gp  = 2 * g + (w >> 1);
            const int src = 16 * (gp & 3) + qr;
            const unsigned t0s = __shfl(pw[0 + (w & 1)], src);
            const unsigned t1s = __shfl(pw[2 + (w & 1)], src);
            pu.u[w] = (gp & 4) ? t1s : t0s;
        }
        const bf16x8 pa = pu.v;

        // O += P . V  (coalesced V^T B-frags)
        o0 = __builtin_amdgcn_mfma_f32_16x16x32_bf16(pa, vf[0], o0, 0, 0, 0);
        o1 = __builtin_amdgcn_mfma_f32_16x16x32_bf16(pa, vf[1], o1, 0, 0, 0);
        o2 = __builtin_amdgcn_mfma_f32_16x16x32_bf16(pa, vf[2], o2, 0, 0, 0);
        o3 = __builtin_amdgcn_mfma_f32_16x16x32_bf16(pa, vf[3], o3, 0, 0, 0);

        if (kt + 1 < t1) {
            #pragma unroll
            for (int i = 0; i < 4; ++i) { kf[i] = kn[i]; vf[i] = vn[i]; }
        }
    }

    // write partials (unnormalized O', m, l)
    const int blin = (b * NQ + qt) * NC + ci;
    float* po = part_O + (size_t)blin * 4096;
    #pragma unroll
    for (int nf = 0; nf < 4; ++nf) {
        const f32x4 ov = (nf == 0) ? o0 : (nf == 1) ? o1 : (nf == 2) ? o2 : o3;
        #pragma unroll
        for (int r = 0; r < 4; ++r)
            po[(size_t)(wv * 16 + 4 * g + r) * 64 + nf * 16 + qr] = ov[r];
    }
    if (g == 0) {
        part_ml[(size_t)blin * 128 + wv * 16 + qr]      = m;
        part_ml[(size_t)blin * 128 + 64 + wv * 16 + qr] = l;
    }
}

// ---------------- Kernel 3: merge partials ----------------
__global__ __launch_bounds__(256) void merge_kernel(
    const float* __restrict__ part_O, const float* __restrict__ part_ml,
    float* __restrict__ out)
{
    const int idx = blockIdx.x * 256 + threadIdx.x;   // 0 .. 524287
    const int row = idx >> 6;
    const int c   = idx & 63;
    const int b   = row >> 11;
    const int t   = row & 2047;
    const int qt  = t >> 6;
    const int qq  = t & 63;
    const int bl0 = (b * NQ + qt) * NC;

    float M = -INFINITY;
    #pragma unroll
    for (int i = 0; i < NC; ++i) {
        const float lvi = part_ml[(size_t)(bl0 + i) * 128 + 64 + qq];
        if (lvi > 0.f) M = fmaxf(M, part_ml[(size_t)(bl0 + i) * 128 + qq]);
    }
    float num = 0.f, den = 0.f;
    #pragma unroll
    for (int i = 0; i < NC; ++i) {
        const float lvi = part_ml[(size_t)(bl0 + i) * 128 + 64 + qq];
        if (lvi > 0.f) {
            const float wgt = __expf(part_ml[(size_t)(bl0 + i) * 128 + qq] - M);
            num += wgt * part_O[(size_t)(bl0 + i) * 4096 + (size_t)qq * 64 + c];
            den += wgt * lvi;
        }
    }
    out[(size_t)row * 64 + c] = num / den;
}

extern "C" void kernel_launch(void* const* d_in, const int* in_sizes, int n_in,
                              void* d_out, int out_size, void* d_ws, size_t ws_size,
                              hipStream_t stream) {
    const float* x  = (const float*)d_in[0];
    const float* Wq = (const float*)d_in[1];
    const float* Wk = (const float*)d_in[2];
    const float* Wv = (const float*)d_in[3];
    float* outp = (float*)d_out;

    unsigned short* wfrag = (unsigned short*)d_ws;      // 192*1024 bf16
    unsigned short* qw  = wfrag + 192 * 1024;           // 8192*64
    unsigned short* kfr = qw + NROWS * Hh;              // 4*131072 (frag-major)
    unsigned short* vfr = kfr + NROWS * Hh;             // 4*131072 (frag-major)
    float* part_O  = (float*)(vfr + NROWS * Hh);        // (Bb*NQ*NC) * 4096
    float* part_ml = part_O + (size_t)(Bb * NQ * NC) * 4096;

    wtrans_kernel<<<dim3(96), 256, 0, stream>>>(Wq, Wk, Wv, wfrag);
    proj_kernel<<<dim3(NROWS / 32), 256, 0, stream>>>(x, wfrag, qw, kfr, vfr);
    attn_kernel<<<dim3(NQ, NC, Bb), 256, 0, stream>>>(qw, kfr, vfr, part_O, part_ml);
    merge_kernel<<<dim3((NROWS * Hh) / 256), 256, 0, stream>>>(part_O, part_ml, outp);
}

// Round 16
// 46.437 us; speedup vs baseline: 1.3095x; 1.0051x over previous
//
#include <hip/hip_runtime.h>
#include <hip/hip_bf16.h>
#include <math.h>

// Problem constants (B=4, T=2048, D=1024, H=64), fp32 in/out.
#define Bb   4
#define Tlen 2048
#define Dd   1024
#define Hh   64
#define NROWS 8192      // B*T
#define NQ   32         // q-tiles of 64 rows per batch
#define MAXCH 8         // max key-chunks per (b,qt)

typedef short bf16x8 __attribute__((ext_vector_type(8)));
typedef float f32x4  __attribute__((ext_vector_type(4)));

__device__ __forceinline__ unsigned short f2b(float f) {
    unsigned u = __float_as_uint(f);
    unsigned r = u + 0x7FFFu + ((u >> 16) & 1u);   // RNE
    return (unsigned short)(r >> 16);
}
__device__ __forceinline__ unsigned pk2(float a, float b) {   // 2xf32 -> packed bf16x2 (RNE)
    __hip_bfloat162 h = __float22bfloat162_rn(make_float2(a, b));
    return *reinterpret_cast<unsigned*>(&h);
}

// ---------------- Kernel 0: W -> MFMA B-fragment layout ----------------
__global__ __launch_bounds__(256) void wtrans_kernel(
    const float* __restrict__ Wq, const float* __restrict__ Wk,
    const float* __restrict__ Wv, unsigned short* __restrict__ wfrag)
{
    const int s = blockIdx.x * 256 + threadIdx.x;    // 0..24575
    const int f   = s / 768;
    const int rem = s % 768;
    const int nb  = rem >> 6;
    const int lane = rem & 63;
    const int g = lane >> 4, qr = lane & 15;
    const int n = nb * 16 + qr;
    const int wsel = n >> 6, h = n & 63;
    const float* W = (wsel == 0) ? Wq : (wsel == 1) ? Wk : Wv;
    const int k0 = (f >> 1) * 64 + (f & 1) * 32 + g * 8;
    unsigned short tmp[8];
    #pragma unroll
    for (int j = 0; j < 8; ++j) tmp[j] = f2b(W[(size_t)(k0 + j) * Hh + h]);
    *(bf16x8*)(wfrag + (size_t)s * 8) = *(const bf16x8*)tmp;
}

// ---------------- Kernel 1: QKV projection (round-15 verbatim) ----------------
// Q row-major [row][h]. K -> kfrag[((b*128+t16)*2+ks)*64+lane]*8+e.
// V -> vfrag[((b*64+kt32)*4+nf)*64+lane]*8+e (V^T B-frag).
__global__ __launch_bounds__(256) void proj_kernel(
    const float* __restrict__ x, const unsigned short* __restrict__ wfrag,
    unsigned short* __restrict__ qw, unsigned short* __restrict__ kfr,
    unsigned short* __restrict__ vfr)
{
    __shared__ unsigned short xs[2][32 * 64];

    const int rb   = blockIdx.x * 32;
    const int tid  = threadIdx.x;
    const int wv   = tid >> 6;
    const int lane = tid & 63;
    const int qr   = lane & 15;
    const int g    = lane >> 4;

    const int xr = tid >> 3, xc8 = tid & 7;
    const float* xg0 = x + (size_t)(rb + xr) * Dd + xc8 * 8;

    const unsigned short* wp = wfrag + ((size_t)(wv * 3) * 64 + lane) * 8;

    f32x4 acc[6] = {};   // [mf][nf]

    float4 px0 = *(const float4*)(xg0 + 0);
    float4 px1 = *(const float4*)(xg0 + 4);

    bf16x8 wr[6];
    #pragma unroll
    for (int ks = 0; ks < 2; ++ks)
        #pragma unroll
        for (int nf = 0; nf < 3; ++nf)
            wr[ks * 3 + nf] = *(const bf16x8*)(wp + (size_t)(ks * 12 + nf) * 512);

    #pragma unroll
    for (int t = 0; t < 16; ++t) {
        const int cur = t & 1;
        {   // stage x(t) from regs
            union { unsigned u[4]; bf16x8 v; } p8;
            p8.u[0] = pk2(px0.x, px0.y);
            p8.u[1] = pk2(px0.z, px0.w);
            p8.u[2] = pk2(px1.x, px1.y);
            p8.u[3] = pk2(px1.z, px1.w);
            *(bf16x8*)(&xs[cur][xr * 64 + ((xc8 ^ (xr & 7)) << 3)]) = p8.v;
        }
        __syncthreads();

        bf16x8 wn[6];
        if (t < 15) {
            px0 = *(const float4*)(xg0 + (t + 1) * 64 + 0);
            px1 = *(const float4*)(xg0 + (t + 1) * 64 + 4);
            const int fb = (t + 1) * 2;
            #pragma unroll
            for (int ks = 0; ks < 2; ++ks)
                #pragma unroll
                for (int nf = 0; nf < 3; ++nf)
                    wn[ks * 3 + nf] = *(const bf16x8*)(wp + (size_t)((fb + ks) * 12 + nf) * 512);
        }

        #pragma unroll
        for (int ks = 0; ks < 2; ++ks) {
            #pragma unroll
            for (int mf = 0; mf < 2; ++mf) {
                const int arow = mf * 16 + qr;
                const bf16x8 a = *(const bf16x8*)(
                    &xs[cur][arow * 64 + (((ks * 4 + g) ^ (arow & 7)) << 3)]);
                acc[mf * 3 + 0] = __builtin_amdgcn_mfma_f32_16x16x32_bf16(a, wr[ks * 3 + 0], acc[mf * 3 + 0], 0, 0, 0);
                acc[mf * 3 + 1] = __builtin_amdgcn_mfma_f32_16x16x32_bf16(a, wr[ks * 3 + 1], acc[mf * 3 + 1], 0, 0, 0);
                acc[mf * 3 + 2] = __builtin_amdgcn_mfma_f32_16x16x32_bf16(a, wr[ks * 3 + 2], acc[mf * 3 + 2], 0, 0, 0);
            }
        }
        __syncthreads();

        if (t < 15) {
            #pragma unroll
            for (int i = 0; i < 6; ++i) wr[i] = wn[i];
        }
    }

    // epilogue: scalar stores; K and V go to fragment-major layouts
    #pragma unroll
    for (int mf = 0; mf < 2; ++mf) {
        #pragma unroll
        for (int nf0 = 0; nf0 < 3; ++nf0) {
            const int n = wv * 48 + nf0 * 16 + qr;
            const int wsel = n >> 6, h = n & 63;
            const f32x4 ov = acc[mf * 3 + nf0];
            #pragma unroll
            for (int r = 0; r < 4; ++r) {
                const int row = rb + mf * 16 + 4 * g + r;
                const unsigned short val = f2b(ov[r]);
                if (wsel == 0) {
                    qw[(size_t)row * Hh + h] = val;
                } else if (wsel == 1) {
                    const int bq = row >> 11, t = row & 2047;
                    const int t16 = t >> 4, qrk = t & 15;
                    const int ks = h >> 5, gk = (h >> 3) & 3, e = h & 7;
                    kfr[((((size_t)bq * 128 + t16) * 2 + ks) * 64 + gk * 16 + qrk) * 8 + e] = val;
                } else {
                    const int bq = row >> 11, t = row & 2047;
                    const int kt = t >> 5, jj = t & 31;
                    const int gv = jj >> 3, e = jj & 7;
                    const int nfv = h >> 4, qrv = h & 15;
                    vfr[((((size_t)bq * 64 + kt) * 4 + nfv) * 64 + gv * 16 + qrv) * 8 + e] = val;
                }
            }
        }
    }
}

// ---------------- Kernel 2: flash attention — no LDS/barriers, KVBLK=64, balanced ----------------
// grid (NQ, MAXCH, B); ntk = qt+1 64-key tiles; nch = min(8, ceil(ntk/2));
// straggler <= 4 tiles. Per tile: 8 K-frags + 8 V-frags (coalesced 1KB wave
// loads, K prefetched a tile ahead, V issued at tile top), 16 MFMA, ONE
// softmax round per 64 keys. Mask VALU only on the diagonal tile.
__global__ __launch_bounds__(256) void attn_kernel(
    const unsigned short* __restrict__ qw, const unsigned short* __restrict__ kfr,
    const unsigned short* __restrict__ vfr,
    float* __restrict__ part_O, float* __restrict__ part_ml)
{
    const int qt = (NQ - 1) - blockIdx.x;   // big q-tiles dispatched first
    const int ci = blockIdx.y;
    const int b  = blockIdx.z;

    const int ntk = qt + 1;                        // causal 64-key tiles
    const int nch = min(MAXCH, (ntk + 1) >> 1);
    const int C   = (ntk + nch - 1) / nch;
    const int nuse = (ntk + C - 1) / C;
    if (ci >= nuse) return;
    const int t0 = ci * C;
    const int t1 = (ntk < t0 + C) ? ntk : (t0 + C);

    const int tid = threadIdx.x;
    const int wv = tid >> 6, lane = tid & 63;
    const int qr = lane & 15, g = lane >> 4;

    const size_t base = (size_t)b * Tlen * Hh;
    const unsigned short* kfb = kfr + (size_t)b * 131072 + lane * 8;
    const unsigned short* vfb = vfr + (size_t)b * 131072 + lane * 8;
    const int qrow = qt * 64 + wv * 16 + qr;

    const bf16x8 qf0 = *(const bf16x8*)(qw + base + (size_t)qrow * Hh + 8 * g);
    const bf16x8 qf1 = *(const bf16x8*)(qw + base + (size_t)qrow * Hh + 32 + 8 * g);

    f32x4 o[4] = {};
    float m = -INFINITY, l = 0.f;

    // K frags of tile kt: idx kt*8 + jf*2 + ks ; V frags: idx kt*8 + half*4 + nf
    bf16x8 kf[8];
    #pragma unroll
    for (int i = 0; i < 8; ++i)
        kf[i] = *(const bf16x8*)(kfb + (size_t)(t0 * 8 + i) * 512);

    for (int kt = t0; kt < t1; ++kt) {
        const int j0 = kt * 64;

        // V(kt): issued now, consumed after softmax (~300cy later)
        bf16x8 vf[8];
        #pragma unroll
        for (int i = 0; i < 8; ++i)
            vf[i] = *(const bf16x8*)(vfb + (size_t)(kt * 8 + i) * 512);

        // S^T = K . Q^T : 4 j-frags x 2 k-steps
        f32x4 a[4] = {};
        #pragma unroll
        for (int jf = 0; jf < 4; ++jf) {
            a[jf] = __builtin_amdgcn_mfma_f32_16x16x32_bf16(kf[jf * 2 + 0], qf0, a[jf], 0, 0, 0);
            a[jf] = __builtin_amdgcn_mfma_f32_16x16x32_bf16(kf[jf * 2 + 1], qf1, a[jf], 0, 0, 0);
        }

        // prefetch K(kt+1) (a full tile of compute to hide under)
        bf16x8 kn[8];
        if (kt + 1 < t1) {
            #pragma unroll
            for (int i = 0; i < 8; ++i)
                kn[i] = *(const bf16x8*)(kfb + (size_t)((kt + 1) * 8 + i) * 512);
        }

        // scores + online softmax; mask only on the diagonal tile
        float p[16];
        float tm = -INFINITY;
        if (kt == qt) {
            #pragma unroll
            for (int jf = 0; jf < 4; ++jf)
                #pragma unroll
                for (int r = 0; r < 4; ++r) {
                    const int jg = j0 + jf * 16 + 4 * g + r;
                    float s = a[jf][r] * 0.125f;
                    s = (jg > qrow) ? -INFINITY : s;
                    p[jf * 4 + r] = s;
                    tm = fmaxf(tm, s);
                }
        } else {
            #pragma unroll
            for (int jf = 0; jf < 4; ++jf)
                #pragma unroll
                for (int r = 0; r < 4; ++r) {
                    const float s = a[jf][r] * 0.125f;
                    p[jf * 4 + r] = s;
                    tm = fmaxf(tm, s);
                }
        }
        tm = fmaxf(tm, __shfl_xor(tm, 16));
        tm = fmaxf(tm, __shfl_xor(tm, 32));
        const float mnew = fmaxf(m, tm);
        const float mc   = fmaxf(mnew, -1e30f);
        float psum = 0.f;
        #pragma unroll
        for (int i = 0; i < 16; ++i) {
            const float pv = __expf(p[i] - mc);
            p[i] = pv; psum += pv;
        }
        psum += __shfl_xor(psum, 16);
        psum += __shfl_xor(psum, 32);

        if (!__all(tm <= m)) {
            const float alpha = (m == -INFINITY) ? 0.f : __expf(m - mc);
            const float ar0 = __shfl(alpha, 4 * g + 0);
            const float ar1 = __shfl(alpha, 4 * g + 1);
            const float ar2 = __shfl(alpha, 4 * g + 2);
            const float ar3 = __shfl(alpha, 4 * g + 3);
            #pragma unroll
            for (int nf = 0; nf < 4; ++nf) {
                o[nf][0] *= ar0; o[nf][1] *= ar1; o[nf][2] *= ar2; o[nf][3] *= ar3;
            }
            l = l * alpha + psum;
        } else {
            l += psum;
        }
        m = mnew;

        // repack P (S^T layout) -> PV A-frags pa0 (j 0..31), pa1 (j 32..63)
        unsigned pw[8];
        #pragma unroll
        for (int jf = 0; jf < 4; ++jf) {
            pw[jf * 2 + 0] = f2b(p[jf * 4 + 0]) | ((unsigned)f2b(p[jf * 4 + 1]) << 16);
            pw[jf * 2 + 1] = f2b(p[jf * 4 + 2]) | ((unsigned)f2b(p[jf * 4 + 3]) << 16);
        }
        union PU { unsigned u[4]; bf16x8 v; } pl, ph;
        #pragma unroll
        for (int w = 0; w < 4; ++w) {
            const int src = 16 * ((g & 1) * 2 + (w >> 1)) + qr;
            const unsigned s0 = __shfl(pw[0 + (w & 1)], src);
            const unsigned s1 = __shfl(pw[2 + (w & 1)], src);
            const unsigned s2 = __shfl(pw[4 + (w & 1)], src);
            const unsigned s3 = __shfl(pw[6 + (w & 1)], src);
            pl.u[w] = (g >> 1) ? s1 : s0;
            ph.u[w] = (g >> 1) ? s3 : s2;
        }
        const bf16x8 pa0 = pl.v, pa1 = ph.v;

        // O += P . V  (V^T B-frags: half 0 = j 0..31, half 1 = j 32..63)
        #pragma unroll
        for (int nf = 0; nf < 4; ++nf) {
            o[nf] = __builtin_amdgcn_mfma_f32_16x16x32_bf16(pa0, vf[0 * 4 + nf], o[nf], 0, 0, 0);
            o[nf] = __builtin_amdgcn_mfma_f32_16x16x32_bf16(pa1, vf[1 * 4 + nf], o[nf], 0, 0, 0);
        }

        if (kt + 1 < t1) {
            #pragma unroll
            for (int i = 0; i < 8; ++i) kf[i] = kn[i];
        }
    }

    // write partials (unnormalized O', m, l)
    const int blin = (b * NQ + qt) * MAXCH + ci;
    float* po = part_O + (size_t)blin * 4096;
    #pragma unroll
    for (int nf = 0; nf < 4; ++nf) {
        #pragma unroll
        for (int r = 0; r < 4; ++r)
            po[(size_t)(wv * 16 + 4 * g + r) * 64 + nf * 16 + qr] = o[nf][r];
    }
    if (g == 0) {
        part_ml[(size_t)blin * 128 + wv * 16 + qr]      = m;
        part_ml[(size_t)blin * 128 + 64 + wv * 16 + qr] = l;
    }
}

// ---------------- Kernel 3: merge partials (variable chunk count) ----------------
__global__ __launch_bounds__(256) void merge_kernel(
    const float* __restrict__ part_O, const float* __restrict__ part_ml,
    float* __restrict__ out)
{
    const int idx = blockIdx.x * 256 + threadIdx.x;   // 0 .. 524287
    const int row = idx >> 6;
    const int c   = idx & 63;
    const int b   = row >> 11;
    const int t   = row & 2047;
    const int qt  = t >> 6;
    const int qq  = t & 63;

    const int ntk = qt + 1;
    const int nch = min(MAXCH, (ntk + 1) >> 1);
    const int C   = (ntk + nch - 1) / nch;
    const int nuse = (ntk + C - 1) / C;
    const int bl0 = (b * NQ + qt) * MAXCH;

    float M = -INFINITY;
    for (int i = 0; i < nuse; ++i)
        M = fmaxf(M, part_ml[(size_t)(bl0 + i) * 128 + qq]);
    float num = 0.f, den = 0.f;
    for (int i = 0; i < nuse; ++i) {
        const float lvi = part_ml[(size_t)(bl0 + i) * 128 + 64 + qq];
        const float wgt = __expf(part_ml[(size_t)(bl0 + i) * 128 + qq] - M);
        num += wgt * part_O[(size_t)(bl0 + i) * 4096 + (size_t)qq * 64 + c];
        den += wgt * lvi;
    }
    out[(size_t)row * 64 + c] = num / den;
}

extern "C" void kernel_launch(void* const* d_in, const int* in_sizes, int n_in,
                              void* d_out, int out_size, void* d_ws, size_t ws_size,
                              hipStream_t stream) {
    const float* x  = (const float*)d_in[0];
    const float* Wq = (const float*)d_in[1];
    const float* Wk = (const float*)d_in[2];
    const float* Wv = (const float*)d_in[3];
    float* outp = (float*)d_out;

    unsigned short* wfrag = (unsigned short*)d_ws;      // 192*1024 bf16
    unsigned short* qw  = wfrag + 192 * 1024;           // 8192*64
    unsigned short* kfr = qw + NROWS * Hh;              // 4*131072 (frag-major)
    unsigned short* vfr = kfr + NROWS * Hh;             // 4*131072 (frag-major)
    float* part_O  = (float*)(vfr + NROWS * Hh);        // (Bb*NQ*MAXCH) * 4096
    float* part_ml = part_O + (size_t)(Bb * NQ * MAXCH) * 4096;

    wtrans_kernel<<<dim3(96), 256, 0, stream>>>(Wq, Wk, Wv, wfrag);
    proj_kernel<<<dim3(NROWS / 32), 256, 0, stream>>>(x, wfrag, qw, kfr, vfr);
    attn_kernel<<<dim3(NQ, MAXCH, Bb), 256, 0, stream>>>(qw, kfr, vfr, part_O, part_ml);
    merge_kernel<<<dim3((NROWS * Hh) / 256), 256, 0, stream>>>(part_O, part_ml, outp);
}

// Round 17
// 45.474 us; speedup vs baseline: 1.3372x; 1.0212x over previous
//
#include <hip/hip_runtime.h>
#include <hip/hip_bf16.h>
#include <math.h>

// Problem constants (B=4, T=2048, D=1024, H=64), fp32 in/out.
#define Bb   4
#define Tlen 2048
#define Dd   1024
#define Hh   64
#define NROWS 8192      // B*T
#define NQ   32         // q-tiles of 64 rows per batch
#define MAXCH 8         // max key-chunks per (b,qt)

typedef short bf16x8 __attribute__((ext_vector_type(8)));
typedef float f32x4  __attribute__((ext_vector_type(4)));

__device__ __forceinline__ unsigned short f2b(float f) {
    unsigned u = __float_as_uint(f);
    unsigned r = u + 0x7FFFu + ((u >> 16) & 1u);   // RNE
    return (unsigned short)(r >> 16);
}
__device__ __forceinline__ unsigned pk2(float a, float b) {   // 2xf32 -> packed bf16x2 (RNE)
    __hip_bfloat162 h = __float22bfloat162_rn(make_float2(a, b));
    return *reinterpret_cast<unsigned*>(&h);
}

// ---------------- Kernel 0: W -> MFMA B-fragment layout ----------------
__global__ __launch_bounds__(256) void wtrans_kernel(
    const float* __restrict__ Wq, const float* __restrict__ Wk,
    const float* __restrict__ Wv, unsigned short* __restrict__ wfrag)
{
    const int s = blockIdx.x * 256 + threadIdx.x;    // 0..24575
    const int f   = s / 768;
    const int rem = s % 768;
    const int nb  = rem >> 6;
    const int lane = rem & 63;
    const int g = lane >> 4, qr = lane & 15;
    const int n = nb * 16 + qr;
    const int wsel = n >> 6, h = n & 63;
    const float* W = (wsel == 0) ? Wq : (wsel == 1) ? Wk : Wv;
    const int k0 = (f >> 1) * 64 + (f & 1) * 32 + g * 8;
    unsigned short tmp[8];
    #pragma unroll
    for (int j = 0; j < 8; ++j) tmp[j] = f2b(W[(size_t)(k0 + j) * Hh + h]);
    *(bf16x8*)(wfrag + (size_t)s * 8) = *(const bf16x8*)tmp;
}

// ---------------- Kernel 1: QKV projection — 2 blocks/CU occupancy fix ----------------
// 512 blocks x 256 threads; block = 16 rows x 192 cols; wave wv = N-quarter
// (3 frags). W register-prefetched one step ahead (round-13). x staged as one
// float4/thread (256B coalesced per row). TLP (2 blocks/CU) covers barrier
// drains and residual load latency that prefetch distance can't.
__global__ __launch_bounds__(256) void proj_kernel(
    const float* __restrict__ x, const unsigned short* __restrict__ wfrag,
    unsigned short* __restrict__ qw, unsigned short* __restrict__ kfr,
    unsigned short* __restrict__ vfr)
{
    __shared__ unsigned short xs[2][16 * 64];

    const int rb   = blockIdx.x * 16;
    const int tid  = threadIdx.x;
    const int wv   = tid >> 6;
    const int lane = tid & 63;
    const int qr   = lane & 15;
    const int g    = lane >> 4;

    // staging: one float4 per thread; 16 lanes cover one row (256 B)
    const int xr = tid >> 4, xc4 = (tid & 15) * 4;
    const float* xg0 = x + (size_t)(rb + xr) * Dd + xc4;
    const int cgs = xc4 >> 3, sub = xc4 & 7;
    const int woff = xr * 64 + ((cgs ^ (xr & 7)) << 3) + sub;

    const unsigned short* wp = wfrag + ((size_t)(wv * 3) * 64 + lane) * 8;

    f32x4 acc[3] = {};

    float4 px = *(const float4*)(xg0);

    bf16x8 wr[6];
    #pragma unroll
    for (int ks = 0; ks < 2; ++ks)
        #pragma unroll
        for (int nf = 0; nf < 3; ++nf)
            wr[ks * 3 + nf] = *(const bf16x8*)(wp + (size_t)(ks * 12 + nf) * 512);

    #pragma unroll
    for (int t = 0; t < 16; ++t) {
        const int cur = t & 1;
        {   // stage x(t): 4 bf16 (8 B) per thread
            const unsigned lo = pk2(px.x, px.y);
            const unsigned hi = pk2(px.z, px.w);
            *(uint2*)(&xs[cur][woff]) = make_uint2(lo, hi);
        }
        __syncthreads();

        bf16x8 wn[6];
        if (t < 15) {
            px = *(const float4*)(xg0 + (t + 1) * 64);
            const int fb = (t + 1) * 2;
            #pragma unroll
            for (int ks = 0; ks < 2; ++ks)
                #pragma unroll
                for (int nf = 0; nf < 3; ++nf)
                    wn[ks * 3 + nf] = *(const bf16x8*)(wp + (size_t)((fb + ks) * 12 + nf) * 512);
        }

        #pragma unroll
        for (int ks = 0; ks < 2; ++ks) {
            const int arow = qr;
            const bf16x8 a = *(const bf16x8*)(
                &xs[cur][arow * 64 + (((ks * 4 + g) ^ (arow & 7)) << 3)]);
            acc[0] = __builtin_amdgcn_mfma_f32_16x16x32_bf16(a, wr[ks * 3 + 0], acc[0], 0, 0, 0);
            acc[1] = __builtin_amdgcn_mfma_f32_16x16x32_bf16(a, wr[ks * 3 + 1], acc[1], 0, 0, 0);
            acc[2] = __builtin_amdgcn_mfma_f32_16x16x32_bf16(a, wr[ks * 3 + 2], acc[2], 0, 0, 0);
        }
        __syncthreads();

        if (t < 15) {
            #pragma unroll
            for (int i = 0; i < 6; ++i) wr[i] = wn[i];
        }
    }

    // epilogue: scalar stores; K and V go to fragment-major layouts
    #pragma unroll
    for (int nf0 = 0; nf0 < 3; ++nf0) {
        const int n = wv * 48 + nf0 * 16 + qr;
        const int wsel = n >> 6, h = n & 63;
        const f32x4 ov = acc[nf0];
        #pragma unroll
        for (int r = 0; r < 4; ++r) {
            const int row = rb + 4 * g + r;
            const unsigned short val = f2b(ov[r]);
            if (wsel == 0) {
                qw[(size_t)row * Hh + h] = val;
            } else if (wsel == 1) {
                const int bq = row >> 11, t = row & 2047;
                const int t16 = t >> 4, qrk = t & 15;
                const int ks = h >> 5, gk = (h >> 3) & 3, e = h & 7;
                kfr[((((size_t)bq * 128 + t16) * 2 + ks) * 64 + gk * 16 + qrk) * 8 + e] = val;
            } else {
                const int bq = row >> 11, t = row & 2047;
                const int kt = t >> 5, jj = t & 31;
                const int gv = jj >> 3, e = jj & 7;
                const int nfv = h >> 4, qrv = h & 15;
                vfr[((((size_t)bq * 64 + kt) * 4 + nfv) * 64 + gv * 16 + qrv) * 8 + e] = val;
            }
        }
    }
}

// ---------------- Kernel 2: flash attention — no LDS/barriers, KVBLK=64, balanced ----------------
__global__ __launch_bounds__(256) void attn_kernel(
    const unsigned short* __restrict__ qw, const unsigned short* __restrict__ kfr,
    const unsigned short* __restrict__ vfr,
    float* __restrict__ part_O, float* __restrict__ part_ml)
{
    const int qt = (NQ - 1) - blockIdx.x;   // big q-tiles dispatched first
    const int ci = blockIdx.y;
    const int b  = blockIdx.z;

    const int ntk = qt + 1;                        // causal 64-key tiles
    const int nch = min(MAXCH, (ntk + 1) >> 1);
    const int C   = (ntk + nch - 1) / nch;
    const int nuse = (ntk + C - 1) / C;
    if (ci >= nuse) return;
    const int t0 = ci * C;
    const int t1 = (ntk < t0 + C) ? ntk : (t0 + C);

    const int tid = threadIdx.x;
    const int wv = tid >> 6, lane = tid & 63;
    const int qr = lane & 15, g = lane >> 4;

    const size_t base = (size_t)b * Tlen * Hh;
    const unsigned short* kfb = kfr + (size_t)b * 131072 + lane * 8;
    const unsigned short* vfb = vfr + (size_t)b * 131072 + lane * 8;
    const int qrow = qt * 64 + wv * 16 + qr;

    const bf16x8 qf0 = *(const bf16x8*)(qw + base + (size_t)qrow * Hh + 8 * g);
    const bf16x8 qf1 = *(const bf16x8*)(qw + base + (size_t)qrow * Hh + 32 + 8 * g);

    f32x4 o[4] = {};
    float m = -INFINITY, l = 0.f;

    bf16x8 kf[8];
    #pragma unroll
    for (int i = 0; i < 8; ++i)
        kf[i] = *(const bf16x8*)(kfb + (size_t)(t0 * 8 + i) * 512);

    for (int kt = t0; kt < t1; ++kt) {
        const int j0 = kt * 64;

        bf16x8 vf[8];
        #pragma unroll
        for (int i = 0; i < 8; ++i)
            vf[i] = *(const bf16x8*)(vfb + (size_t)(kt * 8 + i) * 512);

        f32x4 a[4] = {};
        #pragma unroll
        for (int jf = 0; jf < 4; ++jf) {
            a[jf] = __builtin_amdgcn_mfma_f32_16x16x32_bf16(kf[jf * 2 + 0], qf0, a[jf], 0, 0, 0);
            a[jf] = __builtin_amdgcn_mfma_f32_16x16x32_bf16(kf[jf * 2 + 1], qf1, a[jf], 0, 0, 0);
        }

        bf16x8 kn[8];
        if (kt + 1 < t1) {
            #pragma unroll
            for (int i = 0; i < 8; ++i)
                kn[i] = *(const bf16x8*)(kfb + (size_t)((kt + 1) * 8 + i) * 512);
        }

        float p[16];
        float tm = -INFINITY;
        if (kt == qt) {
            #pragma unroll
            for (int jf = 0; jf < 4; ++jf)
                #pragma unroll
                for (int r = 0; r < 4; ++r) {
                    const int jg = j0 + jf * 16 + 4 * g + r;
                    float s = a[jf][r] * 0.125f;
                    s = (jg > qrow) ? -INFINITY : s;
                    p[jf * 4 + r] = s;
                    tm = fmaxf(tm, s);
                }
        } else {
            #pragma unroll
            for (int jf = 0; jf < 4; ++jf)
                #pragma unroll
                for (int r = 0; r < 4; ++r) {
                    const float s = a[jf][r] * 0.125f;
                    p[jf * 4 + r] = s;
                    tm = fmaxf(tm, s);
                }
        }
        tm = fmaxf(tm, __shfl_xor(tm, 16));
        tm = fmaxf(tm, __shfl_xor(tm, 32));
        const float mnew = fmaxf(m, tm);
        const float mc   = fmaxf(mnew, -1e30f);
        float psum = 0.f;
        #pragma unroll
        for (int i = 0; i < 16; ++i) {
            const float pv = __expf(p[i] - mc);
            p[i] = pv; psum += pv;
        }
        psum += __shfl_xor(psum, 16);
        psum += __shfl_xor(psum, 32);

        if (!__all(tm <= m)) {
            const float alpha = (m == -INFINITY) ? 0.f : __expf(m - mc);
            const float ar0 = __shfl(alpha, 4 * g + 0);
            const float ar1 = __shfl(alpha, 4 * g + 1);
            const float ar2 = __shfl(alpha, 4 * g + 2);
            const float ar3 = __shfl(alpha, 4 * g + 3);
            #pragma unroll
            for (int nf = 0; nf < 4; ++nf) {
                o[nf][0] *= ar0; o[nf][1] *= ar1; o[nf][2] *= ar2; o[nf][3] *= ar3;
            }
            l = l * alpha + psum;
        } else {
            l += psum;
        }
        m = mnew;

        unsigned pw[8];
        #pragma unroll
        for (int jf = 0; jf < 4; ++jf) {
            pw[jf * 2 + 0] = f2b(p[jf * 4 + 0]) | ((unsigned)f2b(p[jf * 4 + 1]) << 16);
            pw[jf * 2 + 1] = f2b(p[jf * 4 + 2]) | ((unsigned)f2b(p[jf * 4 + 3]) << 16);
        }
        union PU { unsigned u[4]; bf16x8 v; } pl, ph;
        #pragma unroll
        for (int w = 0; w < 4; ++w) {
            const int src = 16 * ((g & 1) * 2 + (w >> 1)) + qr;
            const unsigned s0 = __shfl(pw[0 + (w & 1)], src);
            const unsigned s1 = __shfl(pw[2 + (w & 1)], src);
            const unsigned s2 = __shfl(pw[4 + (w & 1)], src);
            const unsigned s3 = __shfl(pw[6 + (w & 1)], src);
            pl.u[w] = (g >> 1) ? s1 : s0;
            ph.u[w] = (g >> 1) ? s3 : s2;
        }
        const bf16x8 pa0 = pl.v, pa1 = ph.v;

        #pragma unroll
        for (int nf = 0; nf < 4; ++nf) {
            o[nf] = __builtin_amdgcn_mfma_f32_16x16x32_bf16(pa0, vf[0 * 4 + nf], o[nf], 0, 0, 0);
            o[nf] = __builtin_amdgcn_mfma_f32_16x16x32_bf16(pa1, vf[1 * 4 + nf], o[nf], 0, 0, 0);
        }

        if (kt + 1 < t1) {
            #pragma unroll
            for (int i = 0; i < 8; ++i) kf[i] = kn[i];
        }
    }

    const int blin = (b * NQ + qt) * MAXCH + ci;
    float* po = part_O + (size_t)blin * 4096;
    #pragma unroll
    for (int nf = 0; nf < 4; ++nf) {
        #pragma unroll
        for (int r = 0; r < 4; ++r)
            po[(size_t)(wv * 16 + 4 * g + r) * 64 + nf * 16 + qr] = o[nf][r];
    }
    if (g == 0) {
        part_ml[(size_t)blin * 128 + wv * 16 + qr]      = m;
        part_ml[(size_t)blin * 128 + 64 + wv * 16 + qr] = l;
    }
}

// ---------------- Kernel 3: merge partials (variable chunk count) ----------------
__global__ __launch_bounds__(256) void merge_kernel(
    const float* __restrict__ part_O, const float* __restrict__ part_ml,
    float* __restrict__ out)
{
    const int idx = blockIdx.x * 256 + threadIdx.x;   // 0 .. 524287
    const int row = idx >> 6;
    const int c   = idx & 63;
    const int b   = row >> 11;
    const int t   = row & 2047;
    const int qt  = t >> 6;
    const int qq  = t & 63;

    const int ntk = qt + 1;
    const int nch = min(MAXCH, (ntk + 1) >> 1);
    const int C   = (ntk + nch - 1) / nch;
    const int nuse = (ntk + C - 1) / C;
    const int bl0 = (b * NQ + qt) * MAXCH;

    float M = -INFINITY;
    for (int i = 0; i < nuse; ++i)
        M = fmaxf(M, part_ml[(size_t)(bl0 + i) * 128 + qq]);
    float num = 0.f, den = 0.f;
    for (int i = 0; i < nuse; ++i) {
        const float lvi = part_ml[(size_t)(bl0 + i) * 128 + 64 + qq];
        const float wgt = __expf(part_ml[(size_t)(bl0 + i) * 128 + qq] - M);
        num += wgt * part_O[(size_t)(bl0 + i) * 4096 + (size_t)qq * 64 + c];
        den += wgt * lvi;
    }
    out[(size_t)row * 64 + c] = num / den;
}

extern "C" void kernel_launch(void* const* d_in, const int* in_sizes, int n_in,
                              void* d_out, int out_size, void* d_ws, size_t ws_size,
                              hipStream_t stream) {
    const float* x  = (const float*)d_in[0];
    const float* Wq = (const float*)d_in[1];
    const float* Wk = (const float*)d_in[2];
    const float* Wv = (const float*)d_in[3];
    float* outp = (float*)d_out;

    unsigned short* wfrag = (unsigned short*)d_ws;      // 192*1024 bf16
    unsigned short* qw  = wfrag + 192 * 1024;           // 8192*64
    unsigned short* kfr = qw + NROWS * Hh;              // 4*131072 (frag-major)
    unsigned short* vfr = kfr + NROWS * Hh;             // 4*131072 (frag-major)
    float* part_O  = (float*)(vfr + NROWS * Hh);        // (Bb*NQ*MAXCH) * 4096
    float* part_ml = part_O + (size_t)(Bb * NQ * MAXCH) * 4096;

    wtrans_kernel<<<dim3(96), 256, 0, stream>>>(Wq, Wk, Wv, wfrag);
    proj_kernel<<<dim3(NROWS / 16), 256, 0, stream>>>(x, wfrag, qw, kfr, vfr);
    attn_kernel<<<dim3(NQ, MAXCH, Bb), 256, 0, stream>>>(qw, kfr, vfr, part_O, part_ml);
    merge_kernel<<<dim3((NROWS * Hh) / 256), 256, 0, stream>>>(part_O, part_ml, outp);
}